// Round 2
// baseline (358.993 us; speedup 1.0000x reference)
//
#include <hip/hip_runtime.h>

// Problem constants (from reference setup_inputs):
//   input_feats: [B=8, L=4096, C=2048] fp32, H=W=64
//   points_yx  : [B=8, M=4, P=512, 2] fp32  (y, x) in [0,1)
//   output     : [B=8, M=4, POOL=64, C=2048] fp32, chunk mean over k=8 points
constexpr int Bc    = 8;
constexpr int Lc    = 4096;
constexpr int Cc    = 2048;
constexpr int Mc    = 4;
constexpr int Pc    = 512;
constexpr int POOLc = 64;
constexpr int Kc    = 8;     // P / POOL
constexpr int Hc    = 64;
constexpr int Wc    = 64;

__device__ __forceinline__ void fma4(float4& acc, float w, const float4 v) {
    acc.x = fmaf(w, v.x, acc.x);
    acc.y = fmaf(w, v.y, acc.y);
    acc.z = fmaf(w, v.z, acc.z);
    acc.w = fmaf(w, v.w, acc.w);
}

__global__ __launch_bounds__(256) void point_sample_pool_kernel(
    const float* __restrict__ feats,   // [B, H*W, C]
    const float* __restrict__ pts,     // [B, M, P, 2]
    float* __restrict__ out)           // [B, M, POOL, C]
{
    const int blk = blockIdx.x;              // [0, B*M*POOL) = [0, 2048)
    const int o   = blk & (POOLc - 1);       // pool bin
    const int bm  = blk >> 6;                // b*M + m
    const int b   = bm >> 2;
    const int tid = threadIdx.x;

    // Two contiguous float4 slices per thread: wave-contiguous 1 KB loads.
    const int cA = tid * 4;                  // [0, 1024)
    const int cB = cA + (Cc / 2);            // [1024, 2048)

    const float* fb = feats + (size_t)b * Lc * Cc;
    const float* pb = pts + ((size_t)bm * Pc + (size_t)o * Kc) * 2;

    float4 accA = make_float4(0.f, 0.f, 0.f, 0.f);
    float4 accB = make_float4(0.f, 0.f, 0.f, 0.f);

#pragma unroll
    for (int j = 0; j < Kc; ++j) {
        // Block-uniform point coords (compiler should scalarize these loads).
        const float py = pb[2 * j + 0];
        const float px = pb[2 * j + 1];
        const float iy = py * (float)(Hc - 1);
        const float ix = px * (float)(Wc - 1);
        const float y0f = floorf(iy);
        const float x0f = floorf(ix);
        const float wy = iy - y0f;
        const float wx = ix - x0f;
        int y0 = (int)y0f; y0 = y0 < 0 ? 0 : (y0 > Hc - 1 ? Hc - 1 : y0);
        int x0 = (int)x0f; x0 = x0 < 0 ? 0 : (x0 > Wc - 1 ? Wc - 1 : x0);
        const int y1 = (y0 + 1 > Hc - 1) ? Hc - 1 : y0 + 1;
        const int x1 = (x0 + 1 > Wc - 1) ? Wc - 1 : x0 + 1;

        const float w00 = (1.f - wx) * (1.f - wy);
        const float w01 = wx * (1.f - wy);
        const float w10 = (1.f - wx) * wy;
        const float w11 = wx * wy;

        const float* r00 = fb + (size_t)(y0 * Wc + x0) * Cc;
        const float* r01 = fb + (size_t)(y0 * Wc + x1) * Cc;
        const float* r10 = fb + (size_t)(y1 * Wc + x0) * Cc;
        const float* r11 = fb + (size_t)(y1 * Wc + x1) * Cc;

        const float4 a00 = *(const float4*)(r00 + cA);
        const float4 b00 = *(const float4*)(r00 + cB);
        const float4 a01 = *(const float4*)(r01 + cA);
        const float4 b01 = *(const float4*)(r01 + cB);
        const float4 a10 = *(const float4*)(r10 + cA);
        const float4 b10 = *(const float4*)(r10 + cB);
        const float4 a11 = *(const float4*)(r11 + cA);
        const float4 b11 = *(const float4*)(r11 + cB);

        fma4(accA, w00, a00); fma4(accB, w00, b00);
        fma4(accA, w01, a01); fma4(accB, w01, b01);
        fma4(accA, w10, a10); fma4(accB, w10, b10);
        fma4(accA, w11, a11); fma4(accB, w11, b11);
    }

    const float inv_k = 1.0f / (float)Kc;
    accA.x *= inv_k; accA.y *= inv_k; accA.z *= inv_k; accA.w *= inv_k;
    accB.x *= inv_k; accB.y *= inv_k; accB.z *= inv_k; accB.w *= inv_k;

    float* ob = out + (size_t)blk * Cc;
    *(float4*)(ob + cA) = accA;
    *(float4*)(ob + cB) = accB;
}

extern "C" void kernel_launch(void* const* d_in, const int* in_sizes, int n_in,
                              void* d_out, int out_size, void* d_ws, size_t ws_size,
                              hipStream_t stream) {
    const float* feats = (const float*)d_in[0];
    const float* pts   = (const float*)d_in[1];
    float* out         = (float*)d_out;

    const int grid = Bc * Mc * POOLc;  // 2048 blocks
    point_sample_pool_kernel<<<grid, 256, 0, stream>>>(feats, pts, out);
}